// Round 5
// baseline (696.910 us; speedup 1.0000x reference)
//
#include <hip/hip_runtime.h>
#include <cstddef>
#include <cstdint>

#define NEGV -1e30f

constexpr int B_    = 32;
constexpr int TXT   = 256;
constexpr int MEL   = 2048;
constexpr int NMEL  = 80;

// ---------------------------------------------------------------------------
// Kernel P: per (b,j): iv[c]=exp(-logvar), m2[c]=2*mu*iv, s = sum(mu^2*iv + logvar)
// Writes IV/M2 transposed to [b][c][j] for coalesced LDS staging in kernel 1.
// ---------------------------------------------------------------------------
__global__ __launch_bounds__(256) void precompute_kernel(
    const float* __restrict__ mu_logvar,
    float* __restrict__ IV, float* __restrict__ M2, float* __restrict__ S)
{
    const int b = blockIdx.x;
    const int j = threadIdx.x;
    const float* row = mu_logvar + (size_t)(b * TXT + j) * (2 * NMEL);
    float s = 0.f;
    for (int c = 0; c < NMEL; ++c) {
        float mu = row[c];
        float lv = row[NMEL + c];
        float iv = expf(-lv);
        IV[(b * NMEL + c) * TXT + j] = iv;
        M2[(b * NMEL + c) * TXT + j] = 2.0f * mu * iv;
        s += mu * mu * iv + lv;
    }
    S[b * TXT + j] = s;
}

// ---------------------------------------------------------------------------
// Kernel 1: log_prob. Tile 64 j x 128 t per block (256 threads).
// Dual-writes: out[b][j][t] (at d_out+1) and lpT[b][t][j] in ws.
// ---------------------------------------------------------------------------
__global__ __launch_bounds__(256) void logprob_kernel(
    const float* __restrict__ mel,
    const float* __restrict__ IV, const float* __restrict__ M2,
    const float* __restrict__ S,
    float* __restrict__ out1,          // d_out + 1 (log_prob region)
    float* __restrict__ lpT,           // ws transposed copy [b][t][j]
    int write_lpT)
{
    const int tt0 = blockIdx.x * 128;
    const int j0  = blockIdx.y * 64;
    const int b   = blockIdx.z;
    const int tx  = threadIdx.x & 15;
    const int ty  = threadIdx.x >> 4;

    __shared__ float sIV[NMEL][64];
    __shared__ float sM2[NMEL][64];

    for (int idx = threadIdx.x; idx < NMEL * 64; idx += 256) {
        int c  = idx >> 6;
        int jj = idx & 63;
        sIV[c][jj] = IV[(b * NMEL + c) * TXT + j0 + jj];
        sM2[c][jj] = M2[(b * NMEL + c) * TXT + j0 + jj];
    }
    __syncthreads();

    float acc[4][8];
#pragma unroll
    for (int a = 0; a < 4; ++a)
#pragma unroll
        for (int d = 0; d < 8; ++d) acc[a][d] = 0.f;

    const float* melb = mel + (size_t)b * NMEL * MEL + tt0 + tx;

#pragma unroll 2
    for (int c = 0; c < NMEL; ++c) {
        float x[8];
#pragma unroll
        for (int d = 0; d < 8; ++d) x[d] = melb[(size_t)c * MEL + 16 * d];
        float4 iv = *(const float4*)&sIV[c][ty * 4];
        float4 m2 = *(const float4*)&sM2[c][ty * 4];
        float ivr[4] = {iv.x, iv.y, iv.z, iv.w};
        float m2r[4] = {m2.x, m2.y, m2.z, m2.w};
#pragma unroll
        for (int a = 0; a < 4; ++a) {
#pragma unroll
            for (int d = 0; d < 8; ++d) {
                float tmp = fmaf(ivr[a], x[d], -m2r[a]);
                acc[a][d] = fmaf(tmp, x[d], acc[a][d]);
            }
        }
    }

    const float c0 = -0.5f / (float)NMEL;
    float4 sj = *(const float4*)&S[b * TXT + j0 + ty * 4];
    float sjr[4] = {sj.x, sj.y, sj.z, sj.w};

#pragma unroll
    for (int a = 0; a < 4; ++a) {
        const int j = j0 + ty * 4 + a;
        float* ob = out1 + (size_t)(b * TXT + j) * MEL + tt0 + tx;
#pragma unroll
        for (int d = 0; d < 8; ++d) {
            float v = c0 * (acc[a][d] + sjr[a]);
            ob[16 * d] = v;
            if (write_lpT) {
                lpT[((size_t)b * MEL + tt0 + tx + 16 * d) * TXT + j] = v;
            }
        }
    }
}

// ---------------------------------------------------------------------------
// DP kernel v5: one wave per batch; lane l owns j = 4l..4l+3 (one float4).
// Prefetch via LDS-DMA ring: __builtin_amdgcn_global_load_lds width=16
// (1 instr = 64 lanes x 16B = one full 256-float row). 64-row x 1KB ring
// (exactly 64 KB), prefetch distance 48 rows. Per 16-step window: one
// s_waitcnt vmcnt(32) (oldest 16 DMAs landed), then 16x { ds_read_b128,
// refill DMA, lse chain }. Empty asm memory barriers pin VMEM issue order
// so the vmcnt FIFO accounting is exact. DMA data never touches VGPRs ->
// nothing for the register allocator to throttle.
// ---------------------------------------------------------------------------
__device__ __forceinline__ float wave_ror1(float x) {
    int xi = __float_as_int(x);
    int r  = __builtin_amdgcn_update_dpp(xi, xi, 0x13C /*wave_ror:1*/, 0xF, 0xF, false);
    return __int_as_float(r);
}

__device__ __forceinline__ float lse2(float a, float b) {
    float mx = fmaxf(a, b);
    float d  = -fabsf(a - b);
    return mx + __logf(1.0f + __expf(d));
}

// one row DMA: lane l loads 16B from g + l*16 -> lds_base + l*16
__device__ __forceinline__ void dma_row(float* lds_base, const float* g_lane) {
    __builtin_amdgcn_global_load_lds(
        (const __attribute__((address_space(1))) void*)g_lane,
        (__attribute__((address_space(3))) void*)lds_base,
        16, 0, 0);
    asm volatile("" ::: "memory");   // pin VMEM issue order (vmcnt FIFO = row order)
}

__global__ __launch_bounds__(64, 1) void dp_kernel(
    const float* __restrict__ lpT,
    const int* __restrict__ tlen, const int* __restrict__ mlen,
    float* __restrict__ alpha)
{
    const int b = blockIdx.x;
    const int l = threadIdx.x;          // 0..63

    const int tl   = tlen[b];
    const int ml   = mlen[b];
    const int tmax = ml - 1;            // last t index (>=1023 for this shape)
    const int jt   = tl - 1;            // last j index
    const float inv_ml = 1.0f / (float)ml;

    __shared__ float ring[64][256];     // 64 KB

    const float* bb = lpT + (size_t)b * MEL * TXT;   // row t at bb + t*TXT
    const bool z = (l == 0);

    // t = 0 init (plain load; compiler handles the wait)
    float ld0 = bb[l * 4];              // only lane 0's .x matters
    float c0 = z ? ld0 : NEGV;
    float c1 = NEGV, c2 = NEGV, c3 = NEGV;

    if (tmax <= 0) {
        const int lf = jt >> 2, ef = jt & 3;
        float v = (ef == 0) ? c0 : NEGV;
        if (l == lf) alpha[b] = v * inv_ml;
        return;
    }

    // preamble: DMA rows 1..48 into slots 1..48 (rows 1..48 always exist)
    for (int r = 1; r <= 48; ++r) {
        dma_row(&ring[r & 63][0], bb + (size_t)r * TXT + 4 * l);
    }

#define DP_CORE(LP)                                            \
    {                                                          \
        float sw = wave_ror1(c3);                              \
        sw = z ? NEGV : sw;                                    \
        float n0 = lse2(c0, sw) + (LP).x;                      \
        float n1 = lse2(c1, c0) + (LP).y;                      \
        float n2 = lse2(c2, c1) + (LP).z;                      \
        float n3 = lse2(c3, c2) + (LP).w;                      \
        c0 = n0; c1 = n1; c2 = n2; c3 = n3;                    \
    }

    int t = 1;
    for (; t + 15 <= tmax; t += 16) {
        // oldest 16 of <=48 outstanding DMAs retired -> rows t..t+15 landed
        asm volatile("s_waitcnt vmcnt(32)" ::: "memory");
#pragma unroll
        for (int s = 0; s < 16; ++s) {
            const int tt = t + s;
            float4 lp = *(const float4*)&ring[tt & 63][l * 4];   // ds_read_b128
            // refill: row tt+48 -> slot (tt+48)&63 (pad guarantees in-bounds;
            // that slot was last read 16 steps ago -> no race)
            dma_row(&ring[(tt + 48) & 63][0], bb + (size_t)(tt + 48) * TXT + 4 * l);
            DP_CORE(lp);
        }
    }

    // tail: <=15 steps; drain all DMAs once, then plain LDS reads
    asm volatile("s_waitcnt vmcnt(0)" ::: "memory");
    for (; t <= tmax; ++t) {
        float4 lp = *(const float4*)&ring[t & 63][l * 4];
        DP_CORE(lp);
    }
#undef DP_CORE

    const int lf = jt >> 2;
    const int ef = jt & 3;
    float v = (ef == 0) ? c0 : (ef == 1) ? c1 : (ef == 2) ? c2 : c3;
    if (l == lf) alpha[b] = v * inv_ml;
}

// ---------------------------------------------------------------------------
// DP fallback (un-transposed reads) if ws too small — correctness safety net.
// ---------------------------------------------------------------------------
__global__ __launch_bounds__(256) void dp_kernel_fallback(
    const float* __restrict__ lp,
    const int* __restrict__ tlen, const int* __restrict__ mlen,
    float* __restrict__ alpha)
{
    const int b    = blockIdx.x;
    const int j    = threadIdx.x;
    const int lane = j & 63;
    const int w    = j >> 6;

    const int tl   = tlen[b];
    const int ml   = mlen[b];
    const int tmax = ml - 1;
    const int jt   = tl - 1;
    const float inv_ml = 1.0f / (float)ml;

    __shared__ float bnd[2][4];
    if (threadIdx.x < 8) bnd[threadIdx.x >> 2][threadIdx.x & 3] = NEGV;
    __syncthreads();

    float cur = (j == 0) ? lp[(size_t)(b * TXT) * MEL] : NEGV;
    if (tmax == 0) {
        if (j == jt) alpha[b] = cur * inv_ml;
        return;
    }
    int p = 0;
    for (int t = 1; t <= tmax; ++t) {
        float lpc = lp[((size_t)(b * TXT + j)) * MEL + t];
        float sh = __shfl_up(cur, 1);
        if (lane == 0) sh = (w > 0) ? bnd[p][w - 1] : NEGV;
        float mx = fmaxf(cur, sh);
        float dd = fminf(cur, sh) - mx;
        float nv = mx + __logf(1.0f + __expf(dd)) + lpc;
        if (lane == 63) bnd[p ^ 1][w] = nv;
        if (t == tmax && j == jt) alpha[b] = nv * inv_ml;
        cur = nv;
        __syncthreads();
        p ^= 1;
    }
}

// ---------------------------------------------------------------------------
// Reduce: loss = -mean_b(alpha[b])
// ---------------------------------------------------------------------------
__global__ void reduce_kernel(const float* __restrict__ alpha, float* __restrict__ out)
{
    const int tid = threadIdx.x;
    float v = (tid < B_) ? alpha[tid] : 0.f;
#pragma unroll
    for (int m = 16; m >= 1; m >>= 1) v += __shfl_xor(v, m);
    if (tid == 0) out[0] = -v / (float)B_;
}

// ---------------------------------------------------------------------------
extern "C" void kernel_launch(void* const* d_in, const int* in_sizes, int n_in,
                              void* d_out, int out_size, void* d_ws, size_t ws_size,
                              hipStream_t stream)
{
    const float* mu_logvar = (const float*)d_in[0];
    const float* melspec   = (const float*)d_in[1];
    const int*   tlen      = (const int*)d_in[2];
    const int*   mlen      = (const int*)d_in[3];
    float* out = (float*)d_out;
    float* ws  = (float*)d_ws;

    // ws layout (floats)
    const size_t IV_OFF    = 0;                        // 32*80*256 = 655360
    const size_t M2_OFF    = 655360;                   // 655360
    const size_t S_OFF     = 1310720;                  // 8192
    const size_t ALPHA_OFF = 1318912;                  // 32
    const size_t LPT_OFF   = 1318944;                  // 16,777,216 + pad
    const size_t LPT_ELEMS = (size_t)B_ * MEL * TXT;
    const size_t LPT_PAD   = (size_t)64 * TXT;         // 64 rows prefetch slack

    float* IV    = ws + IV_OFF;
    float* M2    = ws + M2_OFF;
    float* S     = ws + S_OFF;
    float* alpha = ws + ALPHA_OFF;
    float* lpT   = ws + LPT_OFF;

    const bool use_lpT = ws_size >= (LPT_OFF + LPT_ELEMS + LPT_PAD) * sizeof(float);

    precompute_kernel<<<dim3(B_), dim3(256), 0, stream>>>(mu_logvar, IV, M2, S);

    logprob_kernel<<<dim3(MEL / 128, TXT / 64, B_), dim3(256), 0, stream>>>(
        melspec, IV, M2, S, out + 1, lpT, use_lpT ? 1 : 0);

    if (use_lpT) {
        dp_kernel<<<dim3(B_), dim3(64), 0, stream>>>(lpT, tlen, mlen, alpha);
    } else {
        dp_kernel_fallback<<<dim3(B_), dim3(256), 0, stream>>>(out + 1, tlen, mlen, alpha);
    }

    reduce_kernel<<<dim3(1), dim3(64), 0, stream>>>(alpha, out);
}

// Round 6
// 601.330 us; speedup vs baseline: 1.1589x; 1.1589x over previous
//
#include <hip/hip_runtime.h>
#include <cstddef>
#include <cstdint>

#define NEGV -1e30f

constexpr int B_    = 32;
constexpr int TXT   = 256;
constexpr int MEL   = 2048;
constexpr int NMEL  = 80;

// ---------------------------------------------------------------------------
// Kernel P: per (b,j): iv[c]=exp(-logvar), m2[c]=2*mu*iv, s = sum(mu^2*iv + logvar)
// ---------------------------------------------------------------------------
__global__ __launch_bounds__(256) void precompute_kernel(
    const float* __restrict__ mu_logvar,
    float* __restrict__ IV, float* __restrict__ M2, float* __restrict__ S)
{
    const int b = blockIdx.x;
    const int j = threadIdx.x;
    const float* row = mu_logvar + (size_t)(b * TXT + j) * (2 * NMEL);
    float s = 0.f;
    for (int c = 0; c < NMEL; ++c) {
        float mu = row[c];
        float lv = row[NMEL + c];
        float iv = expf(-lv);
        IV[(b * NMEL + c) * TXT + j] = iv;
        M2[(b * NMEL + c) * TXT + j] = 2.0f * mu * iv;
        s += mu * mu * iv + lv;
    }
    S[b * TXT + j] = s;
}

// ---------------------------------------------------------------------------
// Kernel 1: log_prob. Tile 64 j x 128 t per block (256 threads).
// Dual-writes: out[b][j][t] (at d_out+1) and lpT[b][t][j] in ws.
// ---------------------------------------------------------------------------
__global__ __launch_bounds__(256) void logprob_kernel(
    const float* __restrict__ mel,
    const float* __restrict__ IV, const float* __restrict__ M2,
    const float* __restrict__ S,
    float* __restrict__ out1,          // d_out + 1 (log_prob region)
    float* __restrict__ lpT,           // ws transposed copy [b][t][j]
    int write_lpT)
{
    const int tt0 = blockIdx.x * 128;
    const int j0  = blockIdx.y * 64;
    const int b   = blockIdx.z;
    const int tx  = threadIdx.x & 15;
    const int ty  = threadIdx.x >> 4;

    __shared__ float sIV[NMEL][64];
    __shared__ float sM2[NMEL][64];

    for (int idx = threadIdx.x; idx < NMEL * 64; idx += 256) {
        int c  = idx >> 6;
        int jj = idx & 63;
        sIV[c][jj] = IV[(b * NMEL + c) * TXT + j0 + jj];
        sM2[c][jj] = M2[(b * NMEL + c) * TXT + j0 + jj];
    }
    __syncthreads();

    float acc[4][8];
#pragma unroll
    for (int a = 0; a < 4; ++a)
#pragma unroll
        for (int d = 0; d < 8; ++d) acc[a][d] = 0.f;

    const float* melb = mel + (size_t)b * NMEL * MEL + tt0 + tx;

#pragma unroll 2
    for (int c = 0; c < NMEL; ++c) {
        float x[8];
#pragma unroll
        for (int d = 0; d < 8; ++d) x[d] = melb[(size_t)c * MEL + 16 * d];
        float4 iv = *(const float4*)&sIV[c][ty * 4];
        float4 m2 = *(const float4*)&sM2[c][ty * 4];
        float ivr[4] = {iv.x, iv.y, iv.z, iv.w};
        float m2r[4] = {m2.x, m2.y, m2.z, m2.w};
#pragma unroll
        for (int a = 0; a < 4; ++a) {
#pragma unroll
            for (int d = 0; d < 8; ++d) {
                float tmp = fmaf(ivr[a], x[d], -m2r[a]);
                acc[a][d] = fmaf(tmp, x[d], acc[a][d]);
            }
        }
    }

    const float c0 = -0.5f / (float)NMEL;
    float4 sj = *(const float4*)&S[b * TXT + j0 + ty * 4];
    float sjr[4] = {sj.x, sj.y, sj.z, sj.w};

#pragma unroll
    for (int a = 0; a < 4; ++a) {
        const int j = j0 + ty * 4 + a;
        float* ob = out1 + (size_t)(b * TXT + j) * MEL + tt0 + tx;
#pragma unroll
        for (int d = 0; d < 8; ++d) {
            float v = c0 * (acc[a][d] + sjr[a]);
            ob[16 * d] = v;
            if (write_lpT) {
                lpT[((size_t)b * MEL + tt0 + tx + 16 * d) * TXT + j] = v;
            }
        }
    }
}

// ---------------------------------------------------------------------------
// DP kernel v6: producer-consumer wave specialization.
// Block = 5 waves (320 thr). Wave 0 = consumer: owns the serial lse chain,
// reads rows from a 64-row x 1KB LDS ring via ds_read_b128 (its vmcnt is
// always 0 -> no compiler vmem drains in the hot loop). Waves 1..4 =
// producers: global_load_lds DMA (width 16: 1 instr = one 256-float row),
// 2 rows/wave per 8-row window, 5-window lookahead (~2000cy >> 900cy HBM),
// fine-grained s_waitcnt vmcnt(10) + RAW s_barrier (no __syncthreads, which
// would drain vmcnt(0) and collapse the lookahead).
// Slot-reuse safety: producer issuing window k+5 (slots == window k-3) has
// passed barrier k-1, so consumer has finished windows <= k-2 >= k-3.
// ---------------------------------------------------------------------------
__device__ __forceinline__ float wave_ror1(float x) {
    int xi = __float_as_int(x);
    int r  = __builtin_amdgcn_update_dpp(xi, xi, 0x13C /*wave_ror:1*/, 0xF, 0xF, false);
    return __int_as_float(r);
}

__device__ __forceinline__ float lse2(float a, float b) {
    float mx = fmaxf(a, b);
    float d  = -fabsf(a - b);
    return mx + __logf(1.0f + __expf(d));
}

__device__ __forceinline__ void dma_row(float* lds_base, const float* g_lane) {
    __builtin_amdgcn_global_load_lds(
        (const __attribute__((address_space(1))) void*)g_lane,
        (__attribute__((address_space(3))) void*)lds_base,
        16, 0, 0);
    asm volatile("" ::: "memory");   // pin VMEM issue order (vmcnt FIFO = row order)
}

__global__ __launch_bounds__(320, 1) void dp_kernel(
    const float* __restrict__ lpT,
    const int* __restrict__ tlen, const int* __restrict__ mlen,
    float* __restrict__ alpha)
{
    const int b   = blockIdx.x;
    const int tid = threadIdx.x;
    const int wav = tid >> 6;           // 0 = consumer, 1..4 = producers
    const int l   = tid & 63;

    const int tl   = tlen[b];
    const int ml   = mlen[b];
    const int tmax = ml - 1;            // last t index
    const int jt   = tl - 1;            // last j index
    const float inv_ml = 1.0f / (float)ml;

    __shared__ float ring[64][256];     // 64 KB, slot = row & 63

    const float* bb = lpT + (size_t)b * MEL * TXT;   // row t at bb + t*TXT

    if (tmax <= 0) {                    // before any barrier, all waves
        if (wav == 0) {
            float v = (l == 0 && jt == 0) ? bb[0] : NEGV;
            if (l == (jt >> 2) && (jt & 3) == 0) alpha[b] = v * inv_ml;
            else if (l == (jt >> 2)) alpha[b] = NEGV * inv_ml;
        }
        return;
    }

    // windows: window k covers rows t = 1+8k .. 8+8k; W windows total
    const int W = (tmax + 7) >> 3;      // uniform across block (tmax uniform)

    if (wav != 0) {
        // ----------------- PRODUCER -----------------
        const int p = wav - 1;          // 0..3; rows 1+8w+2p, 2+8w+2p
        // prologue: windows 0..4  (10 DMAs outstanding per wave)
        for (int w = 0; w < 5; ++w) {
            const int r0 = 1 + 8 * w + 2 * p;
            dma_row(&ring[ r0      & 63][0], bb + (size_t)(r0    ) * TXT + 4 * l);
            dma_row(&ring[(r0 + 1) & 63][0], bb + (size_t)(r0 + 1) * TXT + 4 * l);
        }
        for (int k = 0; k < W; ++k) {
            const int r0 = 1 + 8 * (k + 5) + 2 * p;   // window k+5 (pad covers overrun)
            dma_row(&ring[ r0      & 63][0], bb + (size_t)(r0    ) * TXT + 4 * l);
            dma_row(&ring[(r0 + 1) & 63][0], bb + (size_t)(r0 + 1) * TXT + 4 * l);
            // outstanding = windows k..k+5 = 12; release window k's 2
            asm volatile("s_waitcnt vmcnt(10)" ::: "memory");
            asm volatile("s_barrier" ::: "memory");
        }
        return;
    }

    // ----------------- CONSUMER (wave 0) -----------------
    const bool z = (l == 0);
    float ld0 = bb[l * 4];              // row 0 (only lane 0's .x matters)
    float c0 = z ? ld0 : NEGV;
    float c1 = NEGV, c2 = NEGV, c3 = NEGV;

#define DP_CORE(LP)                                            \
    {                                                          \
        float sw = wave_ror1(c3);                              \
        sw = z ? NEGV : sw;                                    \
        float n0 = lse2(c0, sw) + (LP).x;                      \
        float n1 = lse2(c1, c0) + (LP).y;                      \
        float n2 = lse2(c2, c1) + (LP).z;                      \
        float n3 = lse2(c3, c2) + (LP).w;                      \
        c0 = n0; c1 = n1; c2 = n2; c3 = n3;                    \
    }

    for (int k = 0; k < W; ++k) {
        asm volatile("s_barrier" ::: "memory");   // window k now resident
        const int t0 = 1 + 8 * k;
#pragma unroll
        for (int s = 0; s < 8; ++s) {
            const int t = t0 + s;
            if (t <= tmax) {
                float4 lp = *(const float4*)&ring[t & 63][l * 4];  // ds_read_b128
                DP_CORE(lp);
            }
        }
    }
#undef DP_CORE

    const int lf = jt >> 2;
    const int ef = jt & 3;
    float v = (ef == 0) ? c0 : (ef == 1) ? c1 : (ef == 2) ? c2 : c3;
    if (l == lf) alpha[b] = v * inv_ml;
}

// ---------------------------------------------------------------------------
// DP fallback (un-transposed reads) if ws too small — correctness safety net.
// ---------------------------------------------------------------------------
__global__ __launch_bounds__(256) void dp_kernel_fallback(
    const float* __restrict__ lp,
    const int* __restrict__ tlen, const int* __restrict__ mlen,
    float* __restrict__ alpha)
{
    const int b    = blockIdx.x;
    const int j    = threadIdx.x;
    const int lane = j & 63;
    const int w    = j >> 6;

    const int tl   = tlen[b];
    const int ml   = mlen[b];
    const int tmax = ml - 1;
    const int jt   = tl - 1;
    const float inv_ml = 1.0f / (float)ml;

    __shared__ float bnd[2][4];
    if (threadIdx.x < 8) bnd[threadIdx.x >> 2][threadIdx.x & 3] = NEGV;
    __syncthreads();

    float cur = (j == 0) ? lp[(size_t)(b * TXT) * MEL] : NEGV;
    if (tmax == 0) {
        if (j == jt) alpha[b] = cur * inv_ml;
        return;
    }
    int p = 0;
    for (int t = 1; t <= tmax; ++t) {
        float lpc = lp[((size_t)(b * TXT + j)) * MEL + t];
        float sh = __shfl_up(cur, 1);
        if (lane == 0) sh = (w > 0) ? bnd[p][w - 1] : NEGV;
        float mx = fmaxf(cur, sh);
        float dd = fminf(cur, sh) - mx;
        float nv = mx + __logf(1.0f + __expf(dd)) + lpc;
        if (lane == 63) bnd[p ^ 1][w] = nv;
        if (t == tmax && j == jt) alpha[b] = nv * inv_ml;
        cur = nv;
        __syncthreads();
        p ^= 1;
    }
}

// ---------------------------------------------------------------------------
// Reduce: loss = -mean_b(alpha[b])
// ---------------------------------------------------------------------------
__global__ void reduce_kernel(const float* __restrict__ alpha, float* __restrict__ out)
{
    const int tid = threadIdx.x;
    float v = (tid < B_) ? alpha[tid] : 0.f;
#pragma unroll
    for (int m = 16; m >= 1; m >>= 1) v += __shfl_xor(v, m);
    if (tid == 0) out[0] = -v / (float)B_;
}

// ---------------------------------------------------------------------------
extern "C" void kernel_launch(void* const* d_in, const int* in_sizes, int n_in,
                              void* d_out, int out_size, void* d_ws, size_t ws_size,
                              hipStream_t stream)
{
    const float* mu_logvar = (const float*)d_in[0];
    const float* melspec   = (const float*)d_in[1];
    const int*   tlen      = (const int*)d_in[2];
    const int*   mlen      = (const int*)d_in[3];
    float* out = (float*)d_out;
    float* ws  = (float*)d_ws;

    // ws layout (floats)
    const size_t IV_OFF    = 0;                        // 32*80*256 = 655360
    const size_t M2_OFF    = 655360;                   // 655360
    const size_t S_OFF     = 1310720;                  // 8192
    const size_t ALPHA_OFF = 1318912;                  // 32
    const size_t LPT_OFF   = 1318944;                  // 16,777,216 + pad
    const size_t LPT_ELEMS = (size_t)B_ * MEL * TXT;
    const size_t LPT_PAD   = (size_t)64 * TXT;         // 64 rows prefetch slack

    float* IV    = ws + IV_OFF;
    float* M2    = ws + M2_OFF;
    float* S     = ws + S_OFF;
    float* alpha = ws + ALPHA_OFF;
    float* lpT   = ws + LPT_OFF;

    const bool use_lpT = ws_size >= (LPT_OFF + LPT_ELEMS + LPT_PAD) * sizeof(float);

    precompute_kernel<<<dim3(B_), dim3(256), 0, stream>>>(mu_logvar, IV, M2, S);

    logprob_kernel<<<dim3(MEL / 128, TXT / 64, B_), dim3(256), 0, stream>>>(
        melspec, IV, M2, S, out + 1, lpT, use_lpT ? 1 : 0);

    if (use_lpT) {
        dp_kernel<<<dim3(B_), dim3(320), 0, stream>>>(lpT, tlen, mlen, alpha);
    } else {
        dp_kernel_fallback<<<dim3(B_), dim3(256), 0, stream>>>(out + 1, tlen, mlen, alpha);
    }

    reduce_kernel<<<dim3(1), dim3(64), 0, stream>>>(alpha, out);
}